// Round 4
// baseline (234.157 us; speedup 1.0000x reference)
//
#include <hip/hip_runtime.h>

// B=4096, D=64, DM=256, K=32, KA=16, S=50
#define B_N 4096
#define TB 4
#define SQUARINGS 8

// ---- workspace layout (float offsets) ----
#define OFF_W5T  0        // 5 x [256 j][64 k] transposed folded mats: q,klat,vlat,kcode,vcode
#define OFF_B5   81920    // 5 x [256]
#define OFF_KALL 83200    // [48][256] rows 0..15 achart@Wk, 16..47 chart@Wk
#define OFF_VALL 95488    // [48][256] @Wv
#define OFF_M    110848   // [256 k][64 d]  Wo @ form_W
#define OFF_G    127232   // [64][64] form_W^T form_W
#define OFF_RS   131328   // 1/sigma (+pad)
#define OFF_A    131392   // [4096] sigma-scaled part
#define OFF_Bc   135488   // [4096] sigma-free part

// ---- k2 LDS layout (floats) ----
#define S_MT    0         // [64 d][65] transposed M chunk (b32 reads, stride 65 conflict-free)
#define S_QFP   4160      // [4][260]  q, later feat_pre
#define S_SW    5200      // [4][52]   scores/weights
#define S_RED   5408      // [4][16]
// sigma branch: HA 0..4352, HB 4352..8704 (stride 68), scratch 8704..8772
#define SMEM_K2 8772

// ===================== K1: weight folds, 2004 light blocks =====================
__global__ __launch_bounds__(256)
void k1_fold(const float* __restrict__ chart_emb, const float* __restrict__ a_chart_emb,
             const float* __restrict__ zW, const float* __restrict__ zb,
             const float* __restrict__ latW, const float* __restrict__ latb,
             const float* __restrict__ codeW, const float* __restrict__ codeb,
             const float* __restrict__ Wq, const float* __restrict__ Wk,
             const float* __restrict__ Wv, const float* __restrict__ Wo,
             const float* __restrict__ fW, float* __restrict__ ws) {
  __shared__ float red[256];
  const int t = threadIdx.x;
  const int b = blockIdx.x;

  const float* Arow; const float* Bm;
  int astride = 1, bstride = 256, jbase = 0, dstBase, dstStride = 1;
  if (b < 1300) {                       // W5T + biases
    int u = b / 260, r = b - u * 260;
    int i = r >> 2, jc = r & 3; jbase = jc * 64;
    const float* Amat = (u == 0) ? zW : (u <= 2 ? latW : codeW);
    const float* bias = (u == 0) ? zb : (u <= 2 ? latb : codeb);
    Bm = (u == 0) ? Wq : ((u == 1 || u == 3) ? Wk : Wv);
    if (i < 64) {
      Arow = Amat + i * 256;
      dstBase = OFF_W5T + u * 16384 + jbase * 64 + i;
      dstStride = 64;
    } else {
      Arow = bias;
      dstBase = OFF_B5 + u * 256 + jbase;
    }
  } else if (b < 1684) {                // KALL/VALL
    int rr = b - 1300; int row = rr >> 2, jc = rr & 3; jbase = jc * 64;
    int s = (row < 48) ? row : row - 48;
    Bm = (row < 48) ? Wk : Wv;
    Arow = (s < 16) ? (a_chart_emb + s * 256) : (chart_emb + (s - 16) * 256);
    dstBase = OFF_KALL + row * 256 + jbase;
  } else if (b < 1940) {                // M
    int i = b - 1684;
    Arow = Wo + i * 256; Bm = fW; bstride = 64;
    dstBase = OFF_M + i * 64;
  } else {                              // G
    int i = b - 1940;
    Arow = fW + i; astride = 64; Bm = fW; bstride = 64;
    dstBase = OFF_G + i * 64;
  }

  const int j = t & 63, ks = t >> 6;
  const float* ap = Arow + (ks * 64) * astride;
  const float* bp = Bm + (ks * 64) * bstride + jbase + j;
  float a0 = 0.f, a1 = 0.f, a2 = 0.f, a3 = 0.f;
  #pragma unroll 4
  for (int k = 0; k < 64; k += 4) {
    a0 += ap[(k + 0) * astride] * bp[(k + 0) * bstride];
    a1 += ap[(k + 1) * astride] * bp[(k + 1) * bstride];
    a2 += ap[(k + 2) * astride] * bp[(k + 2) * bstride];
    a3 += ap[(k + 3) * astride] * bp[(k + 3) * bstride];
  }
  red[t] = (a0 + a1) + (a2 + a3);
  __syncthreads();
  if (t < 64) {
    float v = red[t] + red[64 + t] + red[128 + t] + red[192 + t];
    ws[dstBase + t * dstStride] = v;
  }
}

// matvec: r[bi] = bias[t] + sum_k xg[bi*64+k] * W5T[u][t][k]
// xg is a block-uniform global pointer (const restrict kernel arg) -> scalar-load bait
__device__ __forceinline__ void mv(const float* __restrict__ ws, int u,
                                   const float* __restrict__ xg, int t, float* r) {
  const float* w = ws + OFF_W5T + u * 16384 + t * 64;
  float bq = ws[OFF_B5 + u * 256 + t];
  #pragma unroll
  for (int bi = 0; bi < TB; ++bi) r[bi] = bq;
  #pragma unroll 4
  for (int k4 = 0; k4 < 16; ++k4) {
    float4 w4 = *(const float4*)(w + k4 * 4);
    #pragma unroll
    for (int bi = 0; bi < TB; ++bi) {
      float4 x4 = *(const float4*)(xg + bi * 64 + k4 * 4);
      r[bi] += x4.x * w4.x + x4.y * w4.y + x4.z * w4.z + x4.w * w4.w;
    }
  }
}

// ===================== K2: everything per-batch (+ sigma block 1024) =====================
__global__ __launch_bounds__(256, 4)
void k2_main(const float* __restrict__ z, const float* __restrict__ rw,
             const float* __restrict__ az, const float* __restrict__ arw,
             const float* __restrict__ acz, const float* __restrict__ ctrl,
             const float* __restrict__ ecov, const float* __restrict__ chanc,
             const float* __restrict__ aanc, const float* __restrict__ fb,
             float* __restrict__ ws) {
  __shared__ __align__(16) float sm[SMEM_K2];
  const int t = threadIdx.x;
  const int wv = t >> 6, ln = t & 63;

  if (blockIdx.x == 1024) {
    // ---------- sigma: 8 trace-normalized squarings of G, Rayleigh vs fp32 G (in ws) ----------
    float* HA = sm;
    float* HB = sm + 4352;
    {
      float tv = (t < 64) ? ws[OFF_G + t * 65] : 0.f;   // diag
      #pragma unroll
      for (int m = 32; m >= 1; m >>= 1) tv += __shfl_xor(tv, m, 64);
      if (t == 0) sm[8704] = (tv > 0.f) ? 1.f / tv : 0.f;
    }
    __syncthreads();
    {
      float inv0 = sm[8704];
      for (int e = t; e < 4096; e += 256) {
        int i = e >> 6, j = e & 63;
        HA[i * 68 + j] = ws[OFF_G + e] * inv0;
      }
    }
    __syncthreads();
    for (int it = 0; it < SQUARINGS; ++it) {
      float* src = (it & 1) ? HB : HA;
      float* dst = (it & 1) ? HA : HB;
      float acc16[16];
      #pragma unroll
      for (int r = 0; r < 16; ++r) acc16[r] = 0.f;
      for (int half = 0; half < 2; ++half) {
        float cb[32];
        #pragma unroll
        for (int k = 0; k < 32; ++k) cb[k] = src[(half * 32 + k) * 68 + ln];
        #pragma unroll
        for (int r = 0; r < 16; ++r) {
          int i = r * 4 + wv;
          float a = 0.f;
          #pragma unroll
          for (int k4 = 0; k4 < 8; ++k4) {
            float4 a4 = *(const float4*)&src[i * 68 + half * 32 + k4 * 4];
            a += a4.x * cb[k4 * 4] + a4.y * cb[k4 * 4 + 1] + a4.z * cb[k4 * 4 + 2] + a4.w * cb[k4 * 4 + 3];
          }
          acc16[r] += a;
        }
      }
      #pragma unroll
      for (int r = 0; r < 16; ++r) dst[(r * 4 + wv) * 68 + ln] = acc16[r];
      __syncthreads();
      {
        float tv = (t < 64) ? dst[t * 68 + t] : 0.f;
        #pragma unroll
        for (int m = 32; m >= 1; m >>= 1) tv += __shfl_xor(tv, m, 64);
        if (t == 0) sm[8704] = (tv > 0.f) ? 1.f / tv : 0.f;
      }
      __syncthreads();
      {
        float sc = sm[8704];
        #pragma unroll
        for (int r = 0; r < 16; ++r) dst[(r * 4 + wv) * 68 + ln] *= sc;
      }
      __syncthreads();
    }
    float* H = (SQUARINGS & 1) ? HB : HA;
    if (t < 64) {                         // max-norm column
      float cn = 0.f;
      for (int i = 0; i < 64; ++i) { float h = H[i * 68 + t]; cn += h * h; }
      float bv = cn; int bj = t;
      #pragma unroll
      for (int m = 32; m >= 1; m >>= 1) {
        float ov = __shfl_xor(bv, m, 64);
        int   oj = __shfl_xor(bj, m, 64);
        if (ov > bv || (ov == bv && oj < bj)) { bv = ov; bj = oj; }
      }
      if (t == 0) sm[8705] = (float)bj;
    }
    __syncthreads();
    {
      int jmax = (int)sm[8705];
      if (t < 64) sm[8708 + t] = H[t * 68 + jmax];
    }
    __syncthreads();
    if (t < 64) {                         // Rayleigh vs original fp32 G from ws
      float vi = sm[8708 + t];
      float y = 0.f;
      #pragma unroll 4
      for (int k = 0; k < 64; ++k) y += ws[OFF_G + t * 64 + k] * sm[8708 + k];
      float num = vi * y, den = vi * vi;
      #pragma unroll
      for (int m = 32; m >= 1; m >>= 1) {
        num += __shfl_xor(num, m, 64);
        den += __shfl_xor(den, m, 64);
      }
      if (t == 0) {
        float lam = (den > 1e-37f) ? num / den : 0.f;
        lam = fmaxf(lam, 0.f);
        float sg = sqrtf(lam);
        ws[OFF_RS] = 1.f / fmaxf(sg, 1e-8f);
      }
    }
    return;
  }

  // ---------- main: 1024 blocks x 4 batches; x operands read uniform from global ----------
  const int b0 = blockIdx.x * TB;
  const float* zg   = z   + b0 * 64;
  const float* azg  = az  + b0 * 64;
  const float* aczg = acz + b0 * 64;

  float qr[TB];
  mv(ws, 0, zg, t, qr);
  #pragma unroll
  for (int bi = 0; bi < TB; ++bi) sm[S_QFP + bi * 260 + t] = qr[bi];
  {
    float kr[TB];
    mv(ws, 1, azg, t, kr);
    #pragma unroll
    for (int bi = 0; bi < TB; ++bi) {
      float p = qr[bi] * kr[bi];
      #pragma unroll
      for (int m = 32; m >= 1; m >>= 1) p += __shfl_xor(p, m, 64);
      if (ln == 0) sm[S_RED + bi * 16 + wv] = p;
    }
  }
  {
    float kr[TB];
    mv(ws, 3, aczg, t, kr);
    #pragma unroll
    for (int bi = 0; bi < TB; ++bi) {
      float p = qr[bi] * kr[bi];
      #pragma unroll
      for (int m = 32; m >= 1; m >>= 1) p += __shfl_xor(p, m, 64);
      if (ln == 0) sm[S_RED + bi * 16 + 4 + wv] = p;
    }
  }
  if (wv == 0) {    // lat/code latent distances (coalesced global reads, wave 0)
    #pragma unroll
    for (int bi = 0; bi < TB; ++bi) {
      float zv = zg[bi * 64 + ln];
      float a = zv - azg[bi * 64 + ln];
      float c = zv - aczg[bi * 64 + ln];
      float dL = a * a, dC = c * c;
      #pragma unroll
      for (int m = 32; m >= 1; m >>= 1) { dL += __shfl_xor(dL, m, 64); dC += __shfl_xor(dC, m, 64); }
      if (ln == 0) { sm[S_RED + bi * 16 + 8] = dL; sm[S_RED + bi * 16 + 9] = dC; }
    }
  }
  float vlr[TB], vcr[TB];
  mv(ws, 2, azg, t, vlr);
  mv(ws, 4, aczg, t, vcr);
  __syncthreads();

  if (t < TB) {
    float pL = sm[S_RED + t * 16 + 0] + sm[S_RED + t * 16 + 1] + sm[S_RED + t * 16 + 2] + sm[S_RED + t * 16 + 3];
    float pC = sm[S_RED + t * 16 + 4] + sm[S_RED + t * 16 + 5] + sm[S_RED + t * 16 + 6] + sm[S_RED + t * 16 + 7];
    sm[S_SW + t * 52 + 48] = pL * 0.0625f - sm[S_RED + t * 16 + 8];
    sm[S_SW + t * 52 + 49] = pC * 0.0625f - sm[S_RED + t * 16 + 9];
  }

  // chart scores: 192 tasks (s,bi); q from LDS (sync'd), z/anchors from global
  if (t < 48 * TB) {
    int s = t >> 2, bi = t & 3;
    const float* krow = ws + OFF_KALL + s * 256;
    float dot = 0.f;
    #pragma unroll 4
    for (int k4 = 0; k4 < 64; ++k4) {
      float4 q4 = *(const float4*)&sm[S_QFP + bi * 260 + k4 * 4];
      float4 kk = *(const float4*)(krow + k4 * 4);
      dot += q4.x * kk.x + q4.y * kk.y + q4.z * kk.z + q4.w * kk.w;
    }
    const float* anc = (s < 16) ? (aanc + s * 64) : (chanc + (s - 16) * 64);
    const float* zrow = zg + bi * 64;
    float d2 = 0.f;
    #pragma unroll 4
    for (int k4 = 0; k4 < 16; ++k4) {
      float4 z4 = *(const float4*)(zrow + k4 * 4);
      float4 a4 = *(const float4*)(anc + k4 * 4);
      float d0 = z4.x - a4.x, d1 = z4.y - a4.y, dd = z4.z - a4.z, d3 = z4.w - a4.w;
      d2 += d0 * d0 + d1 * d1 + dd * dd + d3 * d3;
    }
    float rwv = (s < 16) ? arw[(b0 + bi) * 16 + s] : rw[(b0 + bi) * 32 + (s - 16)];
    sm[S_SW + bi * 52 + s] = rwv * dot * 0.0625f - d2;
  }
  __syncthreads();

  // softmax + fold routing weights
  if (t < TB) {
    float* swr = &sm[S_SW + t * 52];
    float mx = -1e30f;
    for (int s = 0; s < 50; ++s) mx = fmaxf(mx, swr[s]);
    float sum = 0.f;
    for (int s = 0; s < 50; ++s) { float ev = __expf(swr[s] - mx); swr[s] = ev; sum += ev; }
    float inv = 1.f / sum;
    for (int j = 0; j < 16; ++j) swr[j]      *= inv * arw[(b0 + t) * 16 + j];
    for (int k = 0; k < 32; ++k) swr[16 + k] *= inv * rw[(b0 + t) * 32 + k];
    swr[48] *= inv;
    swr[49] *= inv;
  }
  __syncthreads();

  // feat_pre column t for 4 batches -> S_QFP (overwrites q)
  {
    float acc[TB];
    #pragma unroll
    for (int bi = 0; bi < TB; ++bi)
      acc[bi] = sm[S_SW + bi * 52 + 48] * vlr[bi] + sm[S_SW + bi * 52 + 49] * vcr[bi];
    #pragma unroll 2
    for (int sc = 0; sc < 12; ++sc) {
      float v0 = ws[OFF_VALL + (sc * 4 + 0) * 256 + t];
      float v1 = ws[OFF_VALL + (sc * 4 + 1) * 256 + t];
      float v2 = ws[OFF_VALL + (sc * 4 + 2) * 256 + t];
      float v3 = ws[OFF_VALL + (sc * 4 + 3) * 256 + t];
      #pragma unroll
      for (int bi = 0; bi < TB; ++bi) {
        float4 w4 = *(const float4*)&sm[S_SW + bi * 52 + sc * 4];
        acc[bi] += w4.x * v0 + w4.y * v1 + w4.z * v2 + w4.w * v3;
      }
    }
    __syncthreads();
    #pragma unroll
    for (int bi = 0; bi < TB; ++bi) sm[S_QFP + bi * 260 + t] = acc[bi];
  }

  // g = feat_pre @ M; M staged TRANSPOSED (stride 65) per 64-k chunk; 1 output/thread (bi=wv,d=ln)
  float g = 0.f;
  for (int tc = 0; tc < 4; ++tc) {
    __syncthreads();
    {
      int dd = (t & 15) * 4, kr0 = t >> 4;
      #pragma unroll
      for (int p = 0; p < 4; ++p) {
        int kr = kr0 + p * 16;
        float4 m4 = *(const float4*)(ws + OFF_M + (tc * 64 + kr) * 64 + dd);
        sm[S_MT + (dd + 0) * 65 + kr] = m4.x;
        sm[S_MT + (dd + 1) * 65 + kr] = m4.y;
        sm[S_MT + (dd + 2) * 65 + kr] = m4.z;
        sm[S_MT + (dd + 3) * 65 + kr] = m4.w;
      }
    }
    __syncthreads();
    #pragma unroll 4
    for (int k4 = 0; k4 < 16; ++k4) {
      float4 f4 = *(const float4*)&sm[S_QFP + wv * 260 + tc * 64 + k4 * 4];
      float m0 = sm[S_MT + ln * 65 + k4 * 4 + 0];
      float m1 = sm[S_MT + ln * 65 + k4 * 4 + 1];
      float m2 = sm[S_MT + ln * 65 + k4 * 4 + 2];
      float m3 = sm[S_MT + ln * 65 + k4 * 4 + 3];
      g += f4.x * m0 + f4.y * m1 + f4.z * m2 + f4.w * m3;
    }
  }

  // epilogue: per-batch projections -> A (x 1/sigma later), B
  {
    int bb = b0 + wv;
    float fbv = fb[ln];
    float c = ctrl[bb * 64 + ln];
    float e = ecov[bb * 64 + ln];
    float gc = g * c, ge = g * e, ec = e * c, ee = e * e, fc = fbv * c, fe = fbv * e;
    #pragma unroll
    for (int m = 32; m >= 1; m >>= 1) {
      gc += __shfl_xor(gc, m, 64);
      ge += __shfl_xor(ge, m, 64);
      ec += __shfl_xor(ec, m, 64);
      ee += __shfl_xor(ee, m, 64);
      fc += __shfl_xor(fc, m, 64);
      fe += __shfl_xor(fe, m, 64);
    }
    if (ln == 0) {
      float A, Bv;
      if (ee > 1e-8f) { float r = ec / ee; A = gc - ge * r; Bv = fc - fe * r; }
      else { A = gc; Bv = fc; }
      ws[OFF_A  + bb] = A;
      ws[OFF_Bc + bb] = Bv;
    }
  }
}

// ===================== K3: apply 1/sigma =====================
__global__ __launch_bounds__(256)
void k3_out(const float* __restrict__ ws, float* __restrict__ out) {
  int b = blockIdx.x * 256 + threadIdx.x;
  float rs = ws[OFF_RS];
  out[b] = ws[OFF_A + b] * rs + ws[OFF_Bc + b];
}

extern "C" void kernel_launch(void* const* d_in, const int* in_sizes, int n_in,
                              void* d_out, int out_size, void* d_ws, size_t ws_size,
                              hipStream_t stream) {
  const float* z     = (const float*)d_in[0];
  const float* rw    = (const float*)d_in[1];
  const float* az    = (const float*)d_in[2];
  const float* arw   = (const float*)d_in[3];
  const float* acz   = (const float*)d_in[4];
  const float* ctrl  = (const float*)d_in[5];
  const float* ecov  = (const float*)d_in[6];
  const float* chemb = (const float*)d_in[7];
  const float* chanc = (const float*)d_in[8];
  const float* aemb  = (const float*)d_in[9];
  const float* aanc  = (const float*)d_in[10];
  const float* zW    = (const float*)d_in[11];
  const float* zb    = (const float*)d_in[12];
  const float* latW  = (const float*)d_in[13];
  const float* latb  = (const float*)d_in[14];
  const float* codeW = (const float*)d_in[15];
  const float* codeb = (const float*)d_in[16];
  const float* Wq    = (const float*)d_in[17];
  const float* Wk    = (const float*)d_in[18];
  const float* Wv    = (const float*)d_in[19];
  const float* Wo    = (const float*)d_in[20];
  const float* fW    = (const float*)d_in[21];
  const float* fb    = (const float*)d_in[22];
  float* ws  = (float*)d_ws;
  float* out = (float*)d_out;

  k1_fold<<<2004, 256, 0, stream>>>(chemb, aemb, zW, zb, latW, latb, codeW, codeb,
                                    Wq, Wk, Wv, Wo, fW, ws);
  k2_main<<<1025, 256, 0, stream>>>(z, rw, az, arw, acz, ctrl, ecov,
                                    chanc, aanc, fb, ws);
  k3_out<<<16, 256, 0, stream>>>(ws, out);
}

// Round 5
// 211.984 us; speedup vs baseline: 1.1046x; 1.1046x over previous
//
#include <hip/hip_runtime.h>

// B=4096, D=64, DM=256, K=32, KA=16, S=50
#define B_N 4096
#define TB 8
#define SQUARINGS 8

// ---- workspace layout (float offsets) ----
#define OFF_W5   0        // 5 x [64 k][256 j] folded mats (coalesced j): q,klat,vlat,kcode,vcode
#define OFF_B5   81920    // 5 x [256]
#define OFF_KALL 83200    // [48][256] rows 0..15 achart@Wk, 16..47 chart@Wk
#define OFF_VALL 95488    // [48][256] @Wv
#define OFF_M    110848   // [256 k][64 d]  Wo @ form_W
#define OFF_G    127232   // [64][64] form_W^T form_W
#define OFF_RS   131328   // 1/sigma (+pad)
#define OFF_A    131392   // [4096] sigma-scaled part
#define OFF_Bc   135488   // [4096] sigma-free part

// ---- k2 LDS layout (floats) ----
#define S_ZS    0         // [8][68]
#define S_AZS   544
#define S_ACZS  1088
#define S_QFP   1632      // [8][260]  q, later feat_pre
#define S_SW    3712      // [8][52]   scores/weights
#define S_RED   4128      // [8][16]
#define S_MST   4256      // [64][68] M chunk stage -> 8608
// sigma branch: HA 0..4352, HB 4352..8704 (stride 68), scratch 8704..8772
#define SMEM_K2 8772      // 35.1 KB -> 4 blocks/CU by LDS

// ===================== K1: weight folds, 2004 light blocks =====================
__global__ __launch_bounds__(256)
void k1_fold(const float* __restrict__ chart_emb, const float* __restrict__ a_chart_emb,
             const float* __restrict__ zW, const float* __restrict__ zb,
             const float* __restrict__ latW, const float* __restrict__ latb,
             const float* __restrict__ codeW, const float* __restrict__ codeb,
             const float* __restrict__ Wq, const float* __restrict__ Wk,
             const float* __restrict__ Wv, const float* __restrict__ Wo,
             const float* __restrict__ fW, float* __restrict__ ws) {
  __shared__ float red[256];
  const int t = threadIdx.x;
  const int b = blockIdx.x;

  const float* Arow; const float* Bm;
  int astride = 1, bstride = 256, jbase = 0, dstBase;
  if (b < 1300) {                       // W5 + biases (store [k][j], coalesced)
    int u = b / 260, r = b - u * 260;
    int i = r >> 2, jc = r & 3; jbase = jc * 64;
    const float* Amat = (u == 0) ? zW : (u <= 2 ? latW : codeW);
    const float* bias = (u == 0) ? zb : (u <= 2 ? latb : codeb);
    Bm = (u == 0) ? Wq : ((u == 1 || u == 3) ? Wk : Wv);
    if (i < 64) {
      Arow = Amat + i * 256;
      dstBase = OFF_W5 + u * 16384 + i * 256 + jbase;
    } else {
      Arow = bias;
      dstBase = OFF_B5 + u * 256 + jbase;
    }
  } else if (b < 1684) {                // KALL/VALL
    int rr = b - 1300; int row = rr >> 2, jc = rr & 3; jbase = jc * 64;
    int s = (row < 48) ? row : row - 48;
    Bm = (row < 48) ? Wk : Wv;
    Arow = (s < 16) ? (a_chart_emb + s * 256) : (chart_emb + (s - 16) * 256);
    dstBase = OFF_KALL + row * 256 + jbase;
  } else if (b < 1940) {                // M
    int i = b - 1684;
    Arow = Wo + i * 256; Bm = fW; bstride = 64;
    dstBase = OFF_M + i * 64;
  } else {                              // G
    int i = b - 1940;
    Arow = fW + i; astride = 64; Bm = fW; bstride = 64;
    dstBase = OFF_G + i * 64;
  }

  const int j = t & 63, ks = t >> 6;
  const float* ap = Arow + (ks * 64) * astride;
  const float* bp = Bm + (ks * 64) * bstride + jbase + j;
  float a0 = 0.f, a1 = 0.f, a2 = 0.f, a3 = 0.f;
  #pragma unroll 4
  for (int k = 0; k < 64; k += 4) {
    a0 += ap[(k + 0) * astride] * bp[(k + 0) * bstride];
    a1 += ap[(k + 1) * astride] * bp[(k + 1) * bstride];
    a2 += ap[(k + 2) * astride] * bp[(k + 2) * bstride];
    a3 += ap[(k + 3) * astride] * bp[(k + 3) * bstride];
  }
  red[t] = (a0 + a1) + (a2 + a3);
  __syncthreads();
  if (t < 64) {
    float v = red[t] + red[64 + t] + red[128 + t] + red[192 + t];
    ws[dstBase + t] = v;
  }
}

// matvec via register-broadcast: r[bi] = bias[t] + sum_k vx[bi]<lane k> * W5[u][k][t]
// vx[bi] holds x[bi][ln] (lane ln of the wave holds element ln) -> v_readlane broadcast.
__device__ __forceinline__ void mv_rl(const float* __restrict__ ws, int u,
                                      const float* vx, int t, float* r) {
  const float* w = ws + OFF_W5 + u * 16384 + t;
  float bq = ws[OFF_B5 + u * 256 + t];
  #pragma unroll
  for (int bi = 0; bi < TB; ++bi) r[bi] = bq;
  #pragma unroll 16
  for (int k = 0; k < 64; ++k) {
    float wk = w[k * 256];
    #pragma unroll
    for (int bi = 0; bi < TB; ++bi) {
      float xb = __int_as_float(__builtin_amdgcn_readlane(__float_as_int(vx[bi]), k));
      r[bi] = fmaf(xb, wk, r[bi]);
    }
  }
}

// ===================== K2: everything per-batch (+ sigma block 512) =====================
__global__ __launch_bounds__(256, 4)
void k2_main(const float* __restrict__ z, const float* __restrict__ rw,
             const float* __restrict__ az, const float* __restrict__ arw,
             const float* __restrict__ acz, const float* __restrict__ ctrl,
             const float* __restrict__ ecov, const float* __restrict__ chanc,
             const float* __restrict__ aanc, const float* __restrict__ fb,
             float* __restrict__ ws) {
  __shared__ __align__(16) float sm[SMEM_K2];
  const int t = threadIdx.x;
  const int wv = t >> 6, ln = t & 63;

  if (blockIdx.x == 512) {
    // ---------- sigma: 8 trace-normalized squarings of G, Rayleigh vs fp32 G (in ws) ----------
    float* HA = sm;
    float* HB = sm + 4352;
    {
      float tv = (t < 64) ? ws[OFF_G + t * 65] : 0.f;   // diag
      #pragma unroll
      for (int m = 32; m >= 1; m >>= 1) tv += __shfl_xor(tv, m, 64);
      if (t == 0) sm[8704] = (tv > 0.f) ? 1.f / tv : 0.f;
    }
    __syncthreads();
    {
      float inv0 = sm[8704];
      for (int e = t; e < 4096; e += 256) {
        int i = e >> 6, j = e & 63;
        HA[i * 68 + j] = ws[OFF_G + e] * inv0;
      }
    }
    __syncthreads();
    for (int it = 0; it < SQUARINGS; ++it) {
      float* src = (it & 1) ? HB : HA;
      float* dst = (it & 1) ? HA : HB;
      float acc16[16];
      #pragma unroll
      for (int r = 0; r < 16; ++r) acc16[r] = 0.f;
      for (int half = 0; half < 2; ++half) {
        float cb[32];
        #pragma unroll
        for (int k = 0; k < 32; ++k) cb[k] = src[(half * 32 + k) * 68 + ln];
        #pragma unroll
        for (int r = 0; r < 16; ++r) {
          int i = r * 4 + wv;
          float a = 0.f;
          #pragma unroll
          for (int k4 = 0; k4 < 8; ++k4) {
            float4 a4 = *(const float4*)&src[i * 68 + half * 32 + k4 * 4];
            a += a4.x * cb[k4 * 4] + a4.y * cb[k4 * 4 + 1] + a4.z * cb[k4 * 4 + 2] + a4.w * cb[k4 * 4 + 3];
          }
          acc16[r] += a;
        }
      }
      #pragma unroll
      for (int r = 0; r < 16; ++r) dst[(r * 4 + wv) * 68 + ln] = acc16[r];
      __syncthreads();
      {
        float tv = (t < 64) ? dst[t * 68 + t] : 0.f;
        #pragma unroll
        for (int m = 32; m >= 1; m >>= 1) tv += __shfl_xor(tv, m, 64);
        if (t == 0) sm[8704] = (tv > 0.f) ? 1.f / tv : 0.f;
      }
      __syncthreads();
      {
        float sc = sm[8704];
        #pragma unroll
        for (int r = 0; r < 16; ++r) dst[(r * 4 + wv) * 68 + ln] *= sc;
      }
      __syncthreads();
    }
    float* H = (SQUARINGS & 1) ? HB : HA;
    if (t < 64) {                         // max-norm column
      float cn = 0.f;
      for (int i = 0; i < 64; ++i) { float h = H[i * 68 + t]; cn += h * h; }
      float bv = cn; int bj = t;
      #pragma unroll
      for (int m = 32; m >= 1; m >>= 1) {
        float ov = __shfl_xor(bv, m, 64);
        int   oj = __shfl_xor(bj, m, 64);
        if (ov > bv || (ov == bv && oj < bj)) { bv = ov; bj = oj; }
      }
      if (t == 0) sm[8705] = (float)bj;
    }
    __syncthreads();
    {
      int jmax = (int)sm[8705];
      if (t < 64) sm[8708 + t] = H[t * 68 + jmax];
    }
    __syncthreads();
    if (t < 64) {                         // Rayleigh vs original fp32 G
      float vi = sm[8708 + t];
      float y = 0.f;
      #pragma unroll 4
      for (int k = 0; k < 64; ++k) y += ws[OFF_G + t * 64 + k] * sm[8708 + k];
      float num = vi * y, den = vi * vi;
      #pragma unroll
      for (int m = 32; m >= 1; m >>= 1) {
        num += __shfl_xor(num, m, 64);
        den += __shfl_xor(den, m, 64);
      }
      if (t == 0) {
        float lam = (den > 1e-37f) ? num / den : 0.f;
        lam = fmaxf(lam, 0.f);
        float sg = sqrtf(lam);
        ws[OFF_RS] = 1.f / fmaxf(sg, 1e-8f);
      }
    }
    return;
  }

  // ---------- main: 512 blocks x 8 batches ----------
  const int b0 = blockIdx.x * TB;
  const float* zg   = z   + b0 * 64;
  const float* azg  = az  + b0 * 64;
  const float* aczg = acz + b0 * 64;

  for (int e = t; e < TB * 64; e += 256) {
    int bi = e >> 6, d = e & 63; int bb = b0 + bi;
    sm[S_ZS   + bi * 68 + d] = z[bb * 64 + d];
    sm[S_AZS  + bi * 68 + d] = az[bb * 64 + d];
    sm[S_ACZS + bi * 68 + d] = acz[bb * 64 + d];
  }
  __syncthreads();

  // q: x = z rows in VGPRs (lane ln holds element ln), readlane-broadcast matvec
  float qr[TB];
  {
    float vx[TB];
    #pragma unroll
    for (int bi = 0; bi < TB; ++bi) vx[bi] = zg[bi * 64 + ln];
    mv_rl(ws, 0, vx, t, qr);
    #pragma unroll
    for (int bi = 0; bi < TB; ++bi) sm[S_QFP + bi * 260 + t] = qr[bi];
  }
  float vlr[TB], vcr[TB];
  {
    float vx[TB];
    #pragma unroll
    for (int bi = 0; bi < TB; ++bi) vx[bi] = azg[bi * 64 + ln];
    {
      float kr[TB];
      mv_rl(ws, 1, vx, t, kr);            // k_lat -> q.k dot partials
      #pragma unroll
      for (int bi = 0; bi < TB; ++bi) {
        float p = qr[bi] * kr[bi];
        #pragma unroll
        for (int m = 32; m >= 1; m >>= 1) p += __shfl_xor(p, m, 64);
        if (ln == 0) sm[S_RED + bi * 16 + wv] = p;
      }
    }
    mv_rl(ws, 2, vx, t, vlr);             // v_lat
  }
  {
    float vx[TB];
    #pragma unroll
    for (int bi = 0; bi < TB; ++bi) vx[bi] = aczg[bi * 64 + ln];
    {
      float kr[TB];
      mv_rl(ws, 3, vx, t, kr);            // k_code
      #pragma unroll
      for (int bi = 0; bi < TB; ++bi) {
        float p = qr[bi] * kr[bi];
        #pragma unroll
        for (int m = 32; m >= 1; m >>= 1) p += __shfl_xor(p, m, 64);
        if (ln == 0) sm[S_RED + bi * 16 + 4 + wv] = p;
      }
    }
    mv_rl(ws, 4, vx, t, vcr);             // v_code
  }
  if (wv == 0) {    // lat/code latent distances from staged LDS
    #pragma unroll
    for (int bi = 0; bi < TB; ++bi) {
      float zv = sm[S_ZS + bi * 68 + ln];
      float a = zv - sm[S_AZS + bi * 68 + ln];
      float c = zv - sm[S_ACZS + bi * 68 + ln];
      float dL = a * a, dC = c * c;
      #pragma unroll
      for (int m = 32; m >= 1; m >>= 1) { dL += __shfl_xor(dL, m, 64); dC += __shfl_xor(dC, m, 64); }
      if (ln == 0) { sm[S_RED + bi * 16 + 8] = dL; sm[S_RED + bi * 16 + 9] = dC; }
    }
  }
  __syncthreads();

  if (t < TB) {
    float pL = sm[S_RED + t * 16 + 0] + sm[S_RED + t * 16 + 1] + sm[S_RED + t * 16 + 2] + sm[S_RED + t * 16 + 3];
    float pC = sm[S_RED + t * 16 + 4] + sm[S_RED + t * 16 + 5] + sm[S_RED + t * 16 + 6] + sm[S_RED + t * 16 + 7];
    sm[S_SW + t * 52 + 48] = pL * 0.0625f - sm[S_RED + t * 16 + 8];
    sm[S_SW + t * 52 + 49] = pC * 0.0625f - sm[S_RED + t * 16 + 9];
  }

  // chart scores: 384 tasks (s,bi)
  for (int jb = t; jb < 48 * TB; jb += 256) {
    int s = jb >> 3, bi = jb & 7;
    const float* krow = ws + OFF_KALL + s * 256;
    float dot = 0.f;
    #pragma unroll 4
    for (int k4 = 0; k4 < 64; ++k4) {
      float4 q4 = *(const float4*)&sm[S_QFP + bi * 260 + k4 * 4];
      float4 kk = *(const float4*)(krow + k4 * 4);
      dot += q4.x * kk.x + q4.y * kk.y + q4.z * kk.z + q4.w * kk.w;
    }
    const float* anc = (s < 16) ? (aanc + s * 64) : (chanc + (s - 16) * 64);
    float d2 = 0.f;
    #pragma unroll 4
    for (int k4 = 0; k4 < 16; ++k4) {
      float4 z4 = *(const float4*)&sm[S_ZS + bi * 68 + k4 * 4];
      float4 a4 = *(const float4*)(anc + k4 * 4);
      float d0 = z4.x - a4.x, d1 = z4.y - a4.y, dd = z4.z - a4.z, d3 = z4.w - a4.w;
      d2 += d0 * d0 + d1 * d1 + dd * dd + d3 * d3;
    }
    float rwv = (s < 16) ? arw[(b0 + bi) * 16 + s] : rw[(b0 + bi) * 32 + (s - 16)];
    sm[S_SW + bi * 52 + s] = rwv * dot * 0.0625f - d2;
  }
  __syncthreads();

  // softmax + fold routing weights
  if (t < TB) {
    float* swr = &sm[S_SW + t * 52];
    float mx = -1e30f;
    for (int s = 0; s < 50; ++s) mx = fmaxf(mx, swr[s]);
    float sum = 0.f;
    for (int s = 0; s < 50; ++s) { float ev = __expf(swr[s] - mx); swr[s] = ev; sum += ev; }
    float inv = 1.f / sum;
    for (int j = 0; j < 16; ++j) swr[j]      *= inv * arw[(b0 + t) * 16 + j];
    for (int k = 0; k < 32; ++k) swr[16 + k] *= inv * rw[(b0 + t) * 32 + k];
    swr[48] *= inv;
    swr[49] *= inv;
  }
  __syncthreads();

  // feat_pre column t for 8 batches -> S_QFP (overwrites q)
  {
    float acc[TB];
    #pragma unroll
    for (int bi = 0; bi < TB; ++bi)
      acc[bi] = sm[S_SW + bi * 52 + 48] * vlr[bi] + sm[S_SW + bi * 52 + 49] * vcr[bi];
    #pragma unroll 2
    for (int sc = 0; sc < 12; ++sc) {
      float v0 = ws[OFF_VALL + (sc * 4 + 0) * 256 + t];
      float v1 = ws[OFF_VALL + (sc * 4 + 1) * 256 + t];
      float v2 = ws[OFF_VALL + (sc * 4 + 2) * 256 + t];
      float v3 = ws[OFF_VALL + (sc * 4 + 3) * 256 + t];
      #pragma unroll
      for (int bi = 0; bi < TB; ++bi) {
        float4 w4 = *(const float4*)&sm[S_SW + bi * 52 + sc * 4];
        acc[bi] += w4.x * v0 + w4.y * v1 + w4.z * v2 + w4.w * v3;
      }
    }
    __syncthreads();
    #pragma unroll
    for (int bi = 0; bi < TB; ++bi) sm[S_QFP + bi * 260 + t] = acc[bi];
  }

  // g = feat_pre @ M (M staged in 64-row LDS chunks); 2 outputs/thread (bi=wv,wv+4; d=ln)
  float g0 = 0.f, g1 = 0.f;
  const int d = ln;
  for (int tc = 0; tc < 4; ++tc) {
    __syncthreads();
    for (int e = t * 4; e < 4096; e += 1024) {
      int kr = e >> 6, dd = e & 63;
      *(float4*)&sm[S_MST + kr * 68 + dd] = *(const float4*)(ws + OFF_M + (tc * 64 + kr) * 64 + dd);
    }
    __syncthreads();
    #pragma unroll 4
    for (int k4 = 0; k4 < 16; ++k4) {
      float m0 = sm[S_MST + (k4 * 4 + 0) * 68 + d];
      float m1 = sm[S_MST + (k4 * 4 + 1) * 68 + d];
      float m2 = sm[S_MST + (k4 * 4 + 2) * 68 + d];
      float m3 = sm[S_MST + (k4 * 4 + 3) * 68 + d];
      float4 f0 = *(const float4*)&sm[S_QFP + wv * 260 + tc * 64 + k4 * 4];
      float4 f1 = *(const float4*)&sm[S_QFP + (wv + 4) * 260 + tc * 64 + k4 * 4];
      g0 += f0.x * m0 + f0.y * m1 + f0.z * m2 + f0.w * m3;
      g1 += f1.x * m0 + f1.y * m1 + f1.z * m2 + f1.w * m3;
    }
  }

  // epilogue: per-batch projections -> A (x 1/sigma later), B
  {
    float fbv = fb[d];
    #pragma unroll
    for (int s = 0; s < 2; ++s) {
      float g = (s == 0) ? g0 : g1;
      int bi = wv + s * 4;
      int bb = b0 + bi;
      float c = ctrl[bb * 64 + d];
      float e = ecov[bb * 64 + d];
      float gc = g * c, ge = g * e, ec = e * c, ee = e * e, fc = fbv * c, fe = fbv * e;
      #pragma unroll
      for (int m = 32; m >= 1; m >>= 1) {
        gc += __shfl_xor(gc, m, 64);
        ge += __shfl_xor(ge, m, 64);
        ec += __shfl_xor(ec, m, 64);
        ee += __shfl_xor(ee, m, 64);
        fc += __shfl_xor(fc, m, 64);
        fe += __shfl_xor(fe, m, 64);
      }
      if (ln == 0) {
        float A, Bv;
        if (ee > 1e-8f) { float r = ec / ee; A = gc - ge * r; Bv = fc - fe * r; }
        else { A = gc; Bv = fc; }
        ws[OFF_A  + bb] = A;
        ws[OFF_Bc + bb] = Bv;
      }
    }
  }
}

// ===================== K3: apply 1/sigma =====================
__global__ __launch_bounds__(256)
void k3_out(const float* __restrict__ ws, float* __restrict__ out) {
  int b = blockIdx.x * 256 + threadIdx.x;
  float rs = ws[OFF_RS];
  out[b] = ws[OFF_A + b] * rs + ws[OFF_Bc + b];
}

extern "C" void kernel_launch(void* const* d_in, const int* in_sizes, int n_in,
                              void* d_out, int out_size, void* d_ws, size_t ws_size,
                              hipStream_t stream) {
  const float* z     = (const float*)d_in[0];
  const float* rw    = (const float*)d_in[1];
  const float* az    = (const float*)d_in[2];
  const float* arw   = (const float*)d_in[3];
  const float* acz   = (const float*)d_in[4];
  const float* ctrl  = (const float*)d_in[5];
  const float* ecov  = (const float*)d_in[6];
  const float* chemb = (const float*)d_in[7];
  const float* chanc = (const float*)d_in[8];
  const float* aemb  = (const float*)d_in[9];
  const float* aanc  = (const float*)d_in[10];
  const float* zW    = (const float*)d_in[11];
  const float* zb    = (const float*)d_in[12];
  const float* latW  = (const float*)d_in[13];
  const float* latb  = (const float*)d_in[14];
  const float* codeW = (const float*)d_in[15];
  const float* codeb = (const float*)d_in[16];
  const float* Wq    = (const float*)d_in[17];
  const float* Wk    = (const float*)d_in[18];
  const float* Wv    = (const float*)d_in[19];
  const float* Wo    = (const float*)d_in[20];
  const float* fW    = (const float*)d_in[21];
  const float* fb    = (const float*)d_in[22];
  float* ws  = (float*)d_ws;
  float* out = (float*)d_out;

  k1_fold<<<2004, 256, 0, stream>>>(chemb, aemb, zW, zb, latW, latb, codeW, codeb,
                                    Wq, Wk, Wv, Wo, fW, ws);
  k2_main<<<513, 256, 0, stream>>>(z, rw, az, arw, acz, ctrl, ecov,
                                   chanc, aanc, fb, ws);
  k3_out<<<16, 256, 0, stream>>>(ws, out);
}

// Round 6
// 207.028 us; speedup vs baseline: 1.1310x; 1.0239x over previous
//
#include <hip/hip_runtime.h>

// B=4096, D=64, DM=256, K=32, KA=16, S=50
#define B_N 4096
#define SQUARINGS 8

// ---- workspace layout (float offsets) ----
#define OFF_W5   0        // 5 x [64 k][256 m]: ZQ, LK, LV, CK, CV
#define OFF_B5   81920    // 5 x [256]: bq, bl, bvl, bc, bvc
#define OFF_KALL 83200    // [48][256]
#define OFF_VALL 95488    // [48][256]
#define OFF_M    107776   // [256][64]
#define OFF_G    124160   // [64][64]
// second-stage folds:
#define OFF_AL   128256   // [64 zk][64 azk]  ZQ@LK^T
#define OFF_AC   132352   // [64][64]         ZQ@CK^T
#define OFF_LVM  136448   // [64 azk][64 d]   LV@M
#define OFF_CVM  140544   // [64][64]         CV@M
#define OFF_VM   144640   // [48 s][64 d]     VALL@M
#define OFF_R1   147712   // [64 zk][64]: cols 0..47 P=ZQ@KALL^T, 48..63 anchors 0..15
#define OFF_R2   151808   // [64 zk][64]: cols 0..31 anchors 16..47, 32 ul, 33 uc, rest 0
#define OFF_VL   155904   // [64] LK@bq
#define OFF_VC   155968   // [64] CK@bq
#define OFF_CS   156032   // [48] bq.KALL_s
#define OFF_AN2  156080   // [48] |anchor_s|^2
#define OFF_BVML 156128   // [64]
#define OFF_BVMC 156192   // [64]
#define OFF_CLC  156256   // [2] cl, cc
#define OFF_RS   156288   // 1/sigma
#define OFF_A    156320   // [4096]
#define OFF_Bc   160416   // [4096]

// ---- k2 LDS (floats) ----
#define C_CS    0
#define C_AN2   48
#define C_VL    96
#define C_VC    160
#define C_BVML  224
#define C_BVMC  288
#define C_FB    352
#define C_CLC   416
#define S_PART  424       // [4 b][6 v][4 w][64]
#define S_REDV  6568      // [4 b][4 v(t3,t4,r1,r2)][64]
#define S_SCL   7592      // [4 b][16]: 0 bilL,1 bilC,2 zn2,3 dlat,4 dcode,5 azvl,6 aczvc,7 wL,8 wC
#define S_WSW   7656      // [4 b][48]
#define S_GP    7848      // [4 b][4 w][64]
#define SMEM_K2 8872      // sigma branch uses 0..8772

__device__ __forceinline__ float rlane(float v, int l) {
  return __int_as_float(__builtin_amdgcn_readlane(__float_as_int(v), l));
}

// ===================== K1a: stage-1 folds (r5 structure, 2004 blocks) =====================
__global__ __launch_bounds__(256)
void k1a_fold(const float* __restrict__ chart_emb, const float* __restrict__ a_chart_emb,
              const float* __restrict__ zW, const float* __restrict__ zb,
              const float* __restrict__ latW, const float* __restrict__ latb,
              const float* __restrict__ codeW, const float* __restrict__ codeb,
              const float* __restrict__ Wq, const float* __restrict__ Wk,
              const float* __restrict__ Wv, const float* __restrict__ Wo,
              const float* __restrict__ fW, float* __restrict__ ws) {
  __shared__ float red[256];
  const int t = threadIdx.x;
  const int b = blockIdx.x;

  const float* Arow; const float* Bm;
  int astride = 1, bstride = 256, jbase = 0, dstBase;
  if (b < 1300) {
    int u = b / 260, r = b - u * 260;
    int i = r >> 2, jc = r & 3; jbase = jc * 64;
    const float* Amat = (u == 0) ? zW : (u <= 2 ? latW : codeW);
    const float* bias = (u == 0) ? zb : (u <= 2 ? latb : codeb);
    Bm = (u == 0) ? Wq : ((u == 1 || u == 3) ? Wk : Wv);
    if (i < 64) { Arow = Amat + i * 256; dstBase = OFF_W5 + u * 16384 + i * 256 + jbase; }
    else        { Arow = bias;           dstBase = OFF_B5 + u * 256 + jbase; }
  } else if (b < 1684) {
    int rr = b - 1300; int row = rr >> 2, jc = rr & 3; jbase = jc * 64;
    int s = (row < 48) ? row : row - 48;
    Bm = (row < 48) ? Wk : Wv;
    Arow = (s < 16) ? (a_chart_emb + s * 256) : (chart_emb + (s - 16) * 256);
    dstBase = OFF_KALL + row * 256 + jbase;
  } else if (b < 1940) {
    int i = b - 1684;
    Arow = Wo + i * 256; Bm = fW; bstride = 64;
    dstBase = OFF_M + i * 64;
  } else {
    int i = b - 1940;
    Arow = fW + i; astride = 64; Bm = fW; bstride = 64;
    dstBase = OFF_G + i * 64;
  }

  const int j = t & 63, ks = t >> 6;
  const float* ap = Arow + (ks * 64) * astride;
  const float* bp = Bm + (ks * 64) * bstride + jbase + j;
  float a0 = 0.f, a1 = 0.f, a2 = 0.f, a3 = 0.f;
  #pragma unroll 4
  for (int k = 0; k < 64; k += 4) {
    a0 += ap[(k + 0) * astride] * bp[(k + 0) * bstride];
    a1 += ap[(k + 1) * astride] * bp[(k + 1) * bstride];
    a2 += ap[(k + 2) * astride] * bp[(k + 2) * bstride];
    a3 += ap[(k + 3) * astride] * bp[(k + 3) * bstride];
  }
  red[t] = (a0 + a1) + (a2 + a3);
  __syncthreads();
  if (t < 64) ws[dstBase + t] = red[t] + red[64 + t] + red[128 + t] + red[192 + t];
}

// ===================== K1b: stage-2 folds, 370 blocks =====================
__global__ __launch_bounds__(256)
void k1b_fold(const float* __restrict__ chanc, const float* __restrict__ aanc,
              float* __restrict__ ws) {
  __shared__ float red[256];
  const int t = threadIdx.x;
  const int b = blockIdx.x;
  const float* ZQ = ws + OFF_W5;
  const float* LK = ws + OFF_W5 + 16384;
  const float* LV = ws + OFF_W5 + 32768;
  const float* CK = ws + OFF_W5 + 49152;
  const float* CV = ws + OFF_W5 + 65536;
  const float* Mm = ws + OFF_M;
  const float* KAp = ws + OFF_KALL;
  const float* VAp = ws + OFF_VALL;
  const float* bq = ws + OFF_B5;
  const float* bl = ws + OFF_B5 + 256;
  const float* bvl = ws + OFF_B5 + 512;
  const float* bc = ws + OFF_B5 + 768;
  const float* bvc = ws + OFF_B5 + 1024;

  if (b == 368) {
    // R1 anchor cols 48..63 (aanc), R2 cols 0..31 (chanc), zero cols 34..63
    for (int e = t; e < 1024; e += 256) {
      int s = e >> 6, k = e & 63;
      ws[OFF_R1 + k * 64 + 48 + s] = aanc[s * 64 + k];
    }
    for (int e = t; e < 2048; e += 256) {
      int s = e >> 6, k = e & 63;
      ws[OFF_R2 + k * 64 + s] = chanc[s * 64 + k];
    }
    for (int e = t; e < 2048; e += 256) {
      int k = e >> 5, c = 32 + (e & 31);
      if (c >= 34) ws[OFF_R2 + k * 64 + c] = 0.f;
    }
    // ul, uc -> R2 cols 32/33; vl, vc
    int r = t & 63;
    const float* arow; const float* vec; 
    if (t < 64)       { arow = ZQ + r * 256; vec = bl; }
    else if (t < 128) { arow = ZQ + r * 256; vec = bc; }
    else if (t < 192) { arow = LK + r * 256; vec = bq; }
    else              { arow = CK + r * 256; vec = bq; }
    float a0 = 0.f, a1 = 0.f, a2 = 0.f, a3 = 0.f;
    #pragma unroll 4
    for (int m = 0; m < 256; m += 4) {
      a0 += arow[m] * vec[m];     a1 += arow[m + 1] * vec[m + 1];
      a2 += arow[m + 2] * vec[m + 2]; a3 += arow[m + 3] * vec[m + 3];
    }
    float s = (a0 + a1) + (a2 + a3);
    if (t < 64)       ws[OFF_R2 + r * 64 + 32] = s;
    else if (t < 128) ws[OFF_R2 + r * 64 + 33] = s;
    else if (t < 192) ws[OFF_VL + r] = s;
    else              ws[OFF_VC + r] = s;
    return;
  }
  if (b == 369) {
    if (t < 48) {                        // cs
      const float* krow = KAp + t * 256;
      float s = 0.f;
      #pragma unroll 4
      for (int m = 0; m < 256; ++m) s += bq[m] * krow[m];
      ws[OFF_CS + t] = s;
    } else if (t < 96) {                 // an2
      int s_ = t - 48;
      const float* anc = (s_ < 16) ? (aanc + s_ * 64) : (chanc + (s_ - 16) * 64);
      float s = 0.f;
      #pragma unroll 4
      for (int k = 0; k < 64; ++k) s += anc[k] * anc[k];
      ws[OFF_AN2 + s_] = s;
    } else if (t < 160) {                // bvml
      int d = t - 96;
      float s = 0.f;
      #pragma unroll 4
      for (int m = 0; m < 256; ++m) s += bvl[m] * Mm[m * 64 + d];
      ws[OFF_BVML + d] = s;
    } else if (t < 224) {                // bvmc
      int d = t - 160;
      float s = 0.f;
      #pragma unroll 4
      for (int m = 0; m < 256; ++m) s += bvc[m] * Mm[m * 64 + d];
      ws[OFF_BVMC + d] = s;
    } else if (t == 224) {
      float s = 0.f;
      for (int m = 0; m < 256; ++m) s += bq[m] * bl[m];
      ws[OFF_CLC] = s;
    } else if (t == 225) {
      float s = 0.f;
      for (int m = 0; m < 256; ++m) s += bq[m] * bc[m];
      ws[OFF_CLC + 1] = s;
    }
    return;
  }

  // generic 256-dot blocks
  const float* aRow; const float* bBase; bool strideB = false; int outBase, count = 64;
  if (b < 64)        { aRow = ZQ + b * 256;        bBase = LK;  outBase = OFF_AL  + b * 64; }
  else if (b < 128)  { int k = b - 64;  aRow = ZQ + k * 256; bBase = CK; outBase = OFF_AC + k * 64; }
  else if (b < 192)  { int k = b - 128; aRow = LV + k * 256; bBase = Mm; strideB = true; outBase = OFF_LVM + k * 64; }
  else if (b < 256)  { int k = b - 192; aRow = CV + k * 256; bBase = Mm; strideB = true; outBase = OFF_CVM + k * 64; }
  else if (b < 304)  { int s = b - 256; aRow = VAp + s * 256; bBase = Mm; strideB = true; outBase = OFF_VM + s * 64; }
  else               { int k = b - 304; aRow = ZQ + k * 256; bBase = KAp; outBase = OFF_R1 + k * 64; count = 48; }

  const int j = t & 63, ks = t >> 6;
  const float* ap = aRow + ks * 64;
  float acc;
  if (!strideB) {
    const float* bp = bBase + j * 256 + ks * 64;
    float a0 = 0.f, a1 = 0.f, a2 = 0.f, a3 = 0.f;
    #pragma unroll 4
    for (int m = 0; m < 64; m += 4) {
      float4 av = *(const float4*)(ap + m);
      float4 bv = *(const float4*)(bp + m);
      a0 += av.x * bv.x; a1 += av.y * bv.y; a2 += av.z * bv.z; a3 += av.w * bv.w;
    }
    acc = (a0 + a1) + (a2 + a3);
  } else {
    const float* bp = bBase + (ks * 64) * 64 + j;
    float a0 = 0.f, a1 = 0.f, a2 = 0.f, a3 = 0.f;
    #pragma unroll 4
    for (int m = 0; m < 64; m += 4) {
      a0 += ap[m] * bp[m * 64];         a1 += ap[m + 1] * bp[(m + 1) * 64];
      a2 += ap[m + 2] * bp[(m + 2) * 64]; a3 += ap[m + 3] * bp[(m + 3) * 64];
    }
    acc = (a0 + a1) + (a2 + a3);
  }
  red[t] = acc;
  __syncthreads();
  if (t < count) ws[outBase + t] = red[t] + red[64 + t] + red[128 + t] + red[192 + t];
}

// ===================== K2: per-batch, weights-in-registers =====================
__global__ __launch_bounds__(256, 3)
void k2_main(const float* __restrict__ z, const float* __restrict__ rw,
             const float* __restrict__ az, const float* __restrict__ arw,
             const float* __restrict__ acz, const float* __restrict__ ctrl,
             const float* __restrict__ ecov, const float* __restrict__ fb,
             float* __restrict__ ws) {
  __shared__ __align__(16) float sm[SMEM_K2];
  const int t = threadIdx.x;
  const int wv = t >> 6, ln = t & 63;

  if (blockIdx.x == 1024) {
    // ---------- sigma: trace-normalized squarings of G, Rayleigh vs fp32 G ----------
    float* HA = sm;
    float* HB = sm + 4352;
    {
      float tv = (t < 64) ? ws[OFF_G + t * 65] : 0.f;
      #pragma unroll
      for (int m = 32; m >= 1; m >>= 1) tv += __shfl_xor(tv, m, 64);
      if (t == 0) sm[8704] = (tv > 0.f) ? 1.f / tv : 0.f;
    }
    __syncthreads();
    {
      float inv0 = sm[8704];
      for (int e = t; e < 4096; e += 256) {
        int i = e >> 6, j = e & 63;
        HA[i * 68 + j] = ws[OFF_G + e] * inv0;
      }
    }
    __syncthreads();
    for (int it = 0; it < SQUARINGS; ++it) {
      float* src = (it & 1) ? HB : HA;
      float* dst = (it & 1) ? HA : HB;
      float acc16[16];
      #pragma unroll
      for (int r = 0; r < 16; ++r) acc16[r] = 0.f;
      for (int half = 0; half < 2; ++half) {
        float cb[32];
        #pragma unroll
        for (int k = 0; k < 32; ++k) cb[k] = src[(half * 32 + k) * 68 + ln];
        #pragma unroll
        for (int r = 0; r < 16; ++r) {
          int i = r * 4 + wv;
          float a = 0.f;
          #pragma unroll
          for (int k4 = 0; k4 < 8; ++k4) {
            float4 a4 = *(const float4*)&src[i * 68 + half * 32 + k4 * 4];
            a += a4.x * cb[k4 * 4] + a4.y * cb[k4 * 4 + 1] + a4.z * cb[k4 * 4 + 2] + a4.w * cb[k4 * 4 + 3];
          }
          acc16[r] += a;
        }
      }
      #pragma unroll
      for (int r = 0; r < 16; ++r) dst[(r * 4 + wv) * 68 + ln] = acc16[r];
      __syncthreads();
      {
        float tv = (t < 64) ? dst[t * 68 + t] : 0.f;
        #pragma unroll
        for (int m = 32; m >= 1; m >>= 1) tv += __shfl_xor(tv, m, 64);
        if (t == 0) sm[8704] = (tv > 0.f) ? 1.f / tv : 0.f;
      }
      __syncthreads();
      {
        float sc = sm[8704];
        #pragma unroll
        for (int r = 0; r < 16; ++r) dst[(r * 4 + wv) * 68 + ln] *= sc;
      }
      __syncthreads();
    }
    float* H = (SQUARINGS & 1) ? HB : HA;
    if (t < 64) {
      float cn = 0.f;
      for (int i = 0; i < 64; ++i) { float h = H[i * 68 + t]; cn += h * h; }
      float bv = cn; int bj = t;
      #pragma unroll
      for (int m = 32; m >= 1; m >>= 1) {
        float ov = __shfl_xor(bv, m, 64);
        int   oj = __shfl_xor(bj, m, 64);
        if (ov > bv || (ov == bv && oj < bj)) { bv = ov; bj = oj; }
      }
      if (t == 0) sm[8705] = (float)bj;
    }
    __syncthreads();
    {
      int jmax = (int)sm[8705];
      if (t < 64) sm[8708 + t] = H[t * 68 + jmax];
    }
    __syncthreads();
    if (t < 64) {
      float vi = sm[8708 + t];
      float y = 0.f;
      #pragma unroll 4
      for (int k = 0; k < 64; ++k) y += ws[OFF_G + t * 64 + k] * sm[8708 + k];
      float num = vi * y, den = vi * vi;
      #pragma unroll
      for (int m = 32; m >= 1; m >>= 1) {
        num += __shfl_xor(num, m, 64);
        den += __shfl_xor(den, m, 64);
      }
      if (t == 0) {
        float lam = (den > 1e-37f) ? num / den : 0.f;
        lam = fmaxf(lam, 0.f);
        float sg = sqrtf(lam);
        ws[OFF_RS] = 1.f / fmaxf(sg, 1e-8f);
      }
    }
    return;
  }

  // ---- stage consts into LDS ----
  for (int e = t; e < 418; e += 256) {
    float v;
    if (e < 48)       v = ws[OFF_CS + e];
    else if (e < 96)  v = ws[OFF_AN2 + e - 48];
    else if (e < 160) v = ws[OFF_VL + e - 96];
    else if (e < 224) v = ws[OFF_VC + e - 160];
    else if (e < 288) v = ws[OFF_BVML + e - 224];
    else if (e < 352) v = ws[OFF_BVMC + e - 288];
    else if (e < 416) v = fb[e - 352];
    else              v = ws[OFF_CLC + e - 416];
    sm[e] = v;
  }

  // ---- weights into registers (k-slice 16 per wave, lane = output col) ----
  float aLr[16], aCr[16], lvr[16], cvr[16], rAr[16], rBr[16], vmr[12];
  {
    const int kb = wv << 4;
    #pragma unroll
    for (int kk = 0; kk < 16; ++kk) {
      const int k = kb + kk;
      aLr[kk] = ws[OFF_AL  + k * 64 + ln];
      aCr[kk] = ws[OFF_AC  + k * 64 + ln];
      lvr[kk] = ws[OFF_LVM + k * 64 + ln];
      cvr[kk] = ws[OFF_CVM + k * 64 + ln];
      rAr[kk] = ws[OFF_R1  + k * 64 + ln];
      rBr[kk] = ws[OFF_R2  + k * 64 + ln];
    }
    #pragma unroll
    for (int ss = 0; ss < 12; ++ss) vmr[ss] = ws[OFF_VM + (wv * 12 + ss) * 64 + ln];
  }

  const int b0 = blockIdx.x * 4;

  // ---- phase 1: bilinear partials ----
  #pragma unroll
  for (int bi = 0; bi < 4; ++bi) {
    const int gb = b0 + bi;
    const float vz = z[gb * 64 + ln];
    const float va = az[gb * 64 + ln];
    const float vq = acz[gb * 64 + ln];
    float t1 = 0.f, t2 = 0.f, t3 = 0.f, t4 = 0.f, r1 = 0.f, r2 = 0.f;
    #pragma unroll
    for (int kk = 0; kk < 16; ++kk) {
      const int ksrc = (wv << 4) + kk;
      float sz = rlane(vz, ksrc);
      float sa = rlane(va, ksrc);
      float sq = rlane(vq, ksrc);
      t1 = fmaf(sz, aLr[kk], t1);
      t2 = fmaf(sz, aCr[kk], t2);
      r1 = fmaf(sz, rAr[kk], r1);
      r2 = fmaf(sz, rBr[kk], r2);
      t3 = fmaf(sa, lvr[kk], t3);
      t4 = fmaf(sq, cvr[kk], t4);
    }
    const int pb = S_PART + ((bi * 6) * 4 + wv) * 64 + ln;
    sm[pb]        = t1;
    sm[pb + 256]  = t2;
    sm[pb + 512]  = t3;
    sm[pb + 768]  = t4;
    sm[pb + 1024] = r1;
    sm[pb + 1280] = r2;
    if (bi == wv) {   // owner-dots: |z|^2, |z-az|^2, |z-acz|^2
      float zn = vz * vz;
      float dl = (vz - va) * (vz - va);
      float dq = (vz - vq) * (vz - vq);
      #pragma unroll
      for (int m = 32; m >= 1; m >>= 1) {
        zn += __shfl_xor(zn, m, 64);
        dl += __shfl_xor(dl, m, 64);
        dq += __shfl_xor(dq, m, 64);
      }
      if (ln == 0) {
        sm[S_SCL + bi * 16 + 2] = zn;
        sm[S_SCL + bi * 16 + 3] = dl;
        sm[S_SCL + bi * 16 + 4] = dq;
      }
    }
  }
  __syncthreads();

  // ---- phase 2: cross-wave reduce (24 tasks) ----
  for (int tid = wv; tid < 24; tid += 4) {
    const int b = tid / 6, v = tid % 6;
    const int pb = S_PART + ((b * 6 + v) * 4) * 64 + ln;
    float s0 = sm[pb] + sm[pb + 64] + sm[pb + 128] + sm[pb + 192];
    if (v < 2) {
      const float xv = (v == 0) ? az[(b0 + b) * 64 + ln] : acz[(b0 + b) * 64 + ln];
      float d1 = s0 * xv;
      float d2 = xv * sm[((v == 0) ? C_VL : C_VC) + ln];
      #pragma unroll
      for (int m = 32; m >= 1; m >>= 1) {
        d1 += __shfl_xor(d1, m, 64);
        d2 += __shfl_xor(d2, m, 64);
      }
      if (ln == 0) {
        sm[S_SCL + b * 16 + v]     = d1;
        sm[S_SCL + b * 16 + 5 + v] = d2;
      }
    } else {
      sm[S_REDV + (b * 4 + (v - 2)) * 64 + ln] = s0;
    }
  }
  __syncthreads();

  // ---- phase 3: scores + softmax (wave wv -> batch wv) ----
  {
    const int b = wv, gb = b0 + b;
    float rwv = 1.f;
    if (ln < 16)      rwv = arw[gb * 16 + ln];
    else if (ln < 48) rwv = rw[gb * 32 + (ln - 16)];
    float sc_;
    if (ln < 48) {
      float qk = sm[S_REDV + (b * 4 + 2) * 64 + ln] + sm[C_CS + ln];
      float za = (ln < 16) ? sm[S_REDV + (b * 4 + 2) * 64 + 48 + ln]
                           : sm[S_REDV + (b * 4 + 3) * 64 + (ln - 16)];
      float d2 = sm[S_SCL + b * 16 + 2] - 2.f * za + sm[C_AN2 + ln];
      sc_ = rwv * qk * 0.0625f - d2;
    } else if (ln == 48) {
      sc_ = (sm[S_SCL + b * 16 + 0] + sm[S_REDV + (b * 4 + 3) * 64 + 32]
             + sm[S_SCL + b * 16 + 5] + sm[C_CLC]) * 0.0625f - sm[S_SCL + b * 16 + 3];
    } else if (ln == 49) {
      sc_ = (sm[S_SCL + b * 16 + 1] + sm[S_REDV + (b * 4 + 3) * 64 + 33]
             + sm[S_SCL + b * 16 + 6] + sm[C_CLC + 1]) * 0.0625f - sm[S_SCL + b * 16 + 4];
    } else sc_ = -3.0e30f;
    float mx = sc_;
    #pragma unroll
    for (int m = 32; m >= 1; m >>= 1) mx = fmaxf(mx, __shfl_xor(mx, m, 64));
    float ex = (ln < 50) ? __expf(sc_ - mx) : 0.f;
    float sum = ex;
    #pragma unroll
    for (int m = 32; m >= 1; m >>= 1) sum += __shfl_xor(sum, m, 64);
    float wgt = ex / sum;
    if (ln < 48)       sm[S_WSW + b * 48 + ln] = wgt * rwv;
    else if (ln == 48) sm[S_SCL + b * 16 + 7] = wgt;
    else if (ln == 49) sm[S_SCL + b * 16 + 8] = wgt;
  }
  __syncthreads();

  // ---- phase 4: VM partial (s-slice per wave) ----
  #pragma unroll
  for (int bi = 0; bi < 4; ++bi) {
    float gp = 0.f;
    #pragma unroll
    for (int ss = 0; ss < 12; ++ss)
      gp = fmaf(sm[S_WSW + bi * 48 + wv * 12 + ss], vmr[ss], gp);
    sm[S_GP + (bi * 4 + wv) * 64 + ln] = gp;
  }
  __syncthreads();

  // ---- phase 5: assemble g, projection epilogue (wave wv -> batch wv) ----
  {
    const int b = wv, gb = b0 + b;
    const int gp0 = S_GP + (b * 4) * 64 + ln;
    float g = sm[gp0] + sm[gp0 + 64] + sm[gp0 + 128] + sm[gp0 + 192];
    float wL = sm[S_SCL + b * 16 + 7], wC = sm[S_SCL + b * 16 + 8];
    g = fmaf(wL, sm[S_REDV + (b * 4 + 0) * 64 + ln] + sm[C_BVML + ln], g);
    g = fmaf(wC, sm[S_REDV + (b * 4 + 1) * 64 + ln] + sm[C_BVMC + ln], g);
    float c = ctrl[gb * 64 + ln];
    float e = ecov[gb * 64 + ln];
    float fbv = sm[C_FB + ln];
    float gc = g * c, ge = g * e, ec = e * c, ee = e * e, fc = fbv * c, fe = fbv * e;
    #pragma unroll
    for (int m = 32; m >= 1; m >>= 1) {
      gc += __shfl_xor(gc, m, 64);
      ge += __shfl_xor(ge, m, 64);
      ec += __shfl_xor(ec, m, 64);
      ee += __shfl_xor(ee, m, 64);
      fc += __shfl_xor(fc, m, 64);
      fe += __shfl_xor(fe, m, 64);
    }
    if (ln == 0) {
      float A, Bv;
      if (ee > 1e-8f) { float r = ec / ee; A = gc - ge * r; Bv = fc - fe * r; }
      else { A = gc; Bv = fc; }
      ws[OFF_A  + gb] = A;
      ws[OFF_Bc + gb] = Bv;
    }
  }
}

// ===================== K3: apply 1/sigma =====================
__global__ __launch_bounds__(256)
void k3_out(const float* __restrict__ ws, float* __restrict__ out) {
  int b = blockIdx.x * 256 + threadIdx.x;
  float rs = ws[OFF_RS];
  out[b] = ws[OFF_A + b] * rs + ws[OFF_Bc + b];
}

extern "C" void kernel_launch(void* const* d_in, const int* in_sizes, int n_in,
                              void* d_out, int out_size, void* d_ws, size_t ws_size,
                              hipStream_t stream) {
  const float* z     = (const float*)d_in[0];
  const float* rw    = (const float*)d_in[1];
  const float* az    = (const float*)d_in[2];
  const float* arw   = (const float*)d_in[3];
  const float* acz   = (const float*)d_in[4];
  const float* ctrl  = (const float*)d_in[5];
  const float* ecov  = (const float*)d_in[6];
  const float* chemb = (const float*)d_in[7];
  const float* chanc = (const float*)d_in[8];
  const float* aemb  = (const float*)d_in[9];
  const float* aanc  = (const float*)d_in[10];
  const float* zW    = (const float*)d_in[11];
  const float* zb    = (const float*)d_in[12];
  const float* latW  = (const float*)d_in[13];
  const float* latb  = (const float*)d_in[14];
  const float* codeW = (const float*)d_in[15];
  const float* codeb = (const float*)d_in[16];
  const float* Wq    = (const float*)d_in[17];
  const float* Wk    = (const float*)d_in[18];
  const float* Wv    = (const float*)d_in[19];
  const float* Wo    = (const float*)d_in[20];
  const float* fW    = (const float*)d_in[21];
  const float* fb    = (const float*)d_in[22];
  float* ws  = (float*)d_ws;
  float* out = (float*)d_out;

  k1a_fold<<<2004, 256, 0, stream>>>(chemb, aemb, zW, zb, latW, latb, codeW, codeb,
                                     Wq, Wk, Wv, Wo, fW, ws);
  k1b_fold<<<370, 256, 0, stream>>>(chanc, aanc, ws);
  k2_main<<<1025, 256, 0, stream>>>(z, rw, az, arw, acz, ctrl, ecov, fb, ws);
  k3_out<<<16, 256, 0, stream>>>(ws, out);
}